// Round 13
// baseline (1041.468 us; speedup 1.0000x reference)
//
#include <hip/hip_runtime.h>
#include <hip/hip_bf16.h>

#define BB 4
#define SS 2048
#define EE 1024
#define HH 512

typedef __attribute__((ext_vector_type(8))) short short8;
typedef __attribute__((ext_vector_type(4))) float f32x4;
typedef __attribute__((ext_vector_type(16))) float f32x16;
typedef __attribute__((ext_vector_type(4))) unsigned short us4;

static __device__ __forceinline__ unsigned short f2bf(float x){
  unsigned u = __float_as_uint(x);
  u += 0x7fffu + ((u >> 16) & 1u);
  return (unsigned short)(u >> 16);
}

static __device__ __forceinline__ unsigned cvtpk(float lo, float hi){
  unsigned d;
  asm("v_cvt_pk_bf16_f32 %0, %1, %2" : "=v"(d) : "v"(lo), "v"(hi));
  return d;
}

static __device__ __forceinline__ void gload16(const void* g, void* l){
  __builtin_amdgcn_global_load_lds((const __attribute__((address_space(1))) void*)g,
                                   (__attribute__((address_space(3))) void*)l, 16, 0, 0);
}

// ---------------- fused fp32 -> bf16 conversion for all 5 tensors ----------------
__global__ void k_cvt_all(const float* __restrict__ x,  const float* __restrict__ wq,
                          const float* __restrict__ wk, const float* __restrict__ wv,
                          const float* __restrict__ wf,
                          unsigned short* __restrict__ xb,  unsigned short* __restrict__ wqb,
                          unsigned short* __restrict__ wkb, unsigned short* __restrict__ wvb,
                          unsigned short* __restrict__ wfb){
  const int N0 = 1048576;            // x: 4*2048*1024/8
  const int N1 = N0 + 65536;         // wq
  const int N2 = N1 + 65536;         // wk
  const int N3 = N2 + 65536;         // wv
  const int N4 = N3 + 131072;        // wf
  int idx = blockIdx.x * blockDim.x + threadIdx.x;
  int stride = gridDim.x * blockDim.x;
  for (int i = idx; i < N4; i += stride){
    const float* src; unsigned short* dst; int j;
    if (i < N0){ src = x;  dst = xb;  j = i; }
    else if (i < N1){ src = wq; dst = wqb; j = i - N0; }
    else if (i < N2){ src = wk; dst = wkb; j = i - N1; }
    else if (i < N3){ src = wv; dst = wvb; j = i - N2; }
    else            { src = wf; dst = wfb; j = i - N3; }
    const float4* p = (const float4*)src + (long)j * 2;
    float4 a = p[0], b = p[1];
    union { unsigned short u[8]; uint4 v; } r;
    r.u[0]=f2bf(a.x); r.u[1]=f2bf(a.y); r.u[2]=f2bf(a.z); r.u[3]=f2bf(a.w);
    r.u[4]=f2bf(b.x); r.u[5]=f2bf(b.y); r.u[6]=f2bf(b.z); r.u[7]=f2bf(b.w);
    ((uint4*)dst)[j] = r.v;
  }
}

#define GBK 32

// ---------------- merged QKV GEMM (Q, K row-major; V transposed epilogue) ----------
__global__ __launch_bounds__(256, 2) void k_qkvall(
    const unsigned short* __restrict__ xb,
    const unsigned short* __restrict__ wq, const unsigned short* __restrict__ wk,
    const unsigned short* __restrict__ wv,
    const float* __restrict__ bq, const float* __restrict__ bk, const float* __restrict__ bv,
    unsigned short* __restrict__ Q, unsigned short* __restrict__ K,
    unsigned short* __restrict__ Vt)
{
  __shared__ union {
    struct { unsigned short As[2][128 * GBK]; unsigned short Bs[2][128 * GBK]; } g;
    unsigned short Ct[128][136];
  } sm;

  const int z = blockIdx.z;
  const int which = z >> 3, bn = z & 7, b = bn >> 1, n = bn & 1;
  const unsigned short* W; const float* bias; unsigned short* out;
  float os = 1.f; int ldc;
  if (which == 0){ W = wq + n*HH*HH; bias = bq + n*HH; out = Q  + (long)bn*SS*HH;
                   os = 0.044194173824159216f; ldc = HH; }        // fold 1/sqrt(512) into Q
  else if (which == 1){ W = wk + n*HH*HH; bias = bk + n*HH; out = K + (long)bn*SS*HH; ldc = HH; }
  else { W = wv + n*HH*HH; bias = bv + n*HH; out = Vt + (long)bn*SS*HH; ldc = SS; }
  const unsigned short* A = xb + (long)b * SS * EE + n * HH;
  const int row0 = blockIdx.x * 128, col0 = blockIdx.y * 128;

  const int tid = threadIdx.x, lane = tid & 63, w = tid >> 6;
  const int wm = w >> 1, wn = w & 1;
  const int fr = lane & 15, g = lane >> 4;

  f32x4 acc[4][4];
  #pragma unroll
  for (int i = 0; i < 4; i++)
    #pragma unroll
    for (int j = 0; j < 4; j++){ acc[i][j][0]=0.f; acc[i][j][1]=0.f; acc[i][j][2]=0.f; acc[i][j][3]=0.f; }

  const unsigned short* gAsrc[2]; const unsigned short* gBsrc[2];
  unsigned ldsOff[2];
  #pragma unroll
  for (int i = 0; i < 2; i++){
    int slot = w*128 + i*64 + lane;
    int row = slot >> 2, ch = slot & 3;
    int sc_ = ch ^ ((row >> 1) & 3);
    gAsrc[i] = A + (long)(row0 + row) * EE + sc_ * 8;
    gBsrc[i] = W + (long)(col0 + row) * HH + sc_ * 8;
    ldsOff[i] = (unsigned)((w*128 + i*64) * 8);
  }

  unsigned aoff[4], boff[4];
  #pragma unroll
  for (int mi = 0; mi < 4; mi++){
    int row = wm*64 + mi*16 + fr;
    aoff[mi] = row * GBK + ((g ^ ((row >> 1) & 3)) * 8);
  }
  #pragma unroll
  for (int ni = 0; ni < 4; ni++){
    int row = wn*64 + ni*16 + fr;
    boff[ni] = row * GBK + ((g ^ ((row >> 1) & 3)) * 8);
  }

  const int KT = HH / GBK;                      // 16
  #pragma unroll
  for (int i = 0; i < 2; i++) gload16(gAsrc[i], &sm.g.As[0][ldsOff[i]]);
  #pragma unroll
  for (int i = 0; i < 2; i++) gload16(gBsrc[i], &sm.g.Bs[0][ldsOff[i]]);
  __syncthreads();

  for (int kt = 0; kt < KT; ++kt){
    const int cur = kt & 1;
    if (kt + 1 < KT){
      #pragma unroll
      for (int i = 0; i < 2; i++) gload16(gAsrc[i] + (kt+1)*GBK, &sm.g.As[cur^1][ldsOff[i]]);
      #pragma unroll
      for (int i = 0; i < 2; i++) gload16(gBsrc[i] + (kt+1)*GBK, &sm.g.Bs[cur^1][ldsOff[i]]);
    }
    short8 av[4], bv[4];
    #pragma unroll
    for (int mi = 0; mi < 4; mi++) av[mi] = *(const short8*)&sm.g.As[cur][aoff[mi]];
    #pragma unroll
    for (int ni = 0; ni < 4; ni++) bv[ni] = *(const short8*)&sm.g.Bs[cur][boff[ni]];
    #pragma unroll
    for (int mi = 0; mi < 4; mi++)
      #pragma unroll
      for (int ni = 0; ni < 4; ni++)
        acc[mi][ni] = __builtin_amdgcn_mfma_f32_16x16x32_bf16(av[mi], bv[ni], acc[mi][ni], 0, 0, 0);
    __syncthreads();                            // last iter: As/Bs dead after this
  }

  if (which == 2){
    // transposed epilogue: Ct overlays As/Bs (safe: all waves past final barrier)
    #pragma unroll
    for (int mi = 0; mi < 4; mi++){
      #pragma unroll
      for (int ni = 0; ni < 4; ni++){
        int rowb = wm*64 + mi*16 + g*4;         // s-local
        int col  = wn*64 + ni*16 + fr;          // o-local
        float bb = bias[col0 + col];
        us4 pk;
        #pragma unroll
        for (int r = 0; r < 4; r++) pk[r] = f2bf((acc[mi][ni][r] + bb) * os);
        *(us4*)&sm.Ct[col][rowb] = pk;
      }
    }
    __syncthreads();
    #pragma unroll
    for (int it = 0; it < 8; it++){
      int idx2 = it * 256 + tid;                // 128 o x 16 s-chunks
      int o = idx2 >> 4, sch = idx2 & 15;
      uint4 v = *(const uint4*)&sm.Ct[o][sch * 8];
      *(uint4*)&out[(long)(col0 + o) * ldc + row0 + sch * 8] = v;
    }
  } else {
    #pragma unroll
    for (int mi = 0; mi < 4; mi++){
      #pragma unroll
      for (int ni = 0; ni < 4; ni++){
        int row = row0 + wm*64 + mi*16 + g*4;
        int col = col0 + wn*64 + ni*16 + fr;
        float bb = bias[col];
        #pragma unroll
        for (int r = 0; r < 4; r++){
          float v = (acc[mi][ni][r] + bb) * os;
          out[(long)(row + r) * ldc + col] = f2bf(v);
        }
      }
    }
  }
}

// ---------------- output projection GEMM (f32 out), R12-exact ----------------
__global__ __launch_bounds__(256, 2) void k_outproj(
    const unsigned short* __restrict__ O, const unsigned short* __restrict__ wf,
    const float* __restrict__ bfb, float* __restrict__ out)
{
  __shared__ unsigned short As[2][128 * GBK];
  __shared__ unsigned short Bs[2][128 * GBK];
  const int tid = threadIdx.x, lane = tid & 63, w = tid >> 6;
  const int wm = w >> 1, wn = w & 1;
  const int fr = lane & 15, g = lane >> 4;
  const int row0 = blockIdx.x * 128, col0 = blockIdx.y * 128;

  f32x4 acc[4][4];
  #pragma unroll
  for (int i = 0; i < 4; i++)
    #pragma unroll
    for (int j = 0; j < 4; j++){ acc[i][j][0]=0.f; acc[i][j][1]=0.f; acc[i][j][2]=0.f; acc[i][j][3]=0.f; }

  const unsigned short* gAsrc[2]; const unsigned short* gBsrc[2];
  unsigned ldsOff[2];
  #pragma unroll
  for (int i = 0; i < 2; i++){
    int slot = w*128 + i*64 + lane;
    int row = slot >> 2, ch = slot & 3;
    int sc_ = ch ^ ((row >> 1) & 3);
    gAsrc[i] = O  + (long)(row0 + row) * EE + sc_ * 8;
    gBsrc[i] = wf + (long)(col0 + row) * EE + sc_ * 8;
    ldsOff[i] = (unsigned)((w*128 + i*64) * 8);
  }

  unsigned aoff[4], boff[4];
  #pragma unroll
  for (int mi = 0; mi < 4; mi++){
    int row = wm*64 + mi*16 + fr;
    aoff[mi] = row * GBK + ((g ^ ((row >> 1) & 3)) * 8);
  }
  #pragma unroll
  for (int ni = 0; ni < 4; ni++){
    int row = wn*64 + ni*16 + fr;
    boff[ni] = row * GBK + ((g ^ ((row >> 1) & 3)) * 8);
  }

  const int KT = EE / GBK;
  #pragma unroll
  for (int i = 0; i < 2; i++) gload16(gAsrc[i], &As[0][ldsOff[i]]);
  #pragma unroll
  for (int i = 0; i < 2; i++) gload16(gBsrc[i], &Bs[0][ldsOff[i]]);
  __syncthreads();

  for (int kt = 0; kt < KT; ++kt){
    const int cur = kt & 1;
    if (kt + 1 < KT){
      #pragma unroll
      for (int i = 0; i < 2; i++) gload16(gAsrc[i] + (kt+1)*GBK, &As[cur^1][ldsOff[i]]);
      #pragma unroll
      for (int i = 0; i < 2; i++) gload16(gBsrc[i] + (kt+1)*GBK, &Bs[cur^1][ldsOff[i]]);
    }
    short8 av[4], bv[4];
    #pragma unroll
    for (int mi = 0; mi < 4; mi++) av[mi] = *(const short8*)&As[cur][aoff[mi]];
    #pragma unroll
    for (int ni = 0; ni < 4; ni++) bv[ni] = *(const short8*)&Bs[cur][boff[ni]];
    #pragma unroll
    for (int mi = 0; mi < 4; mi++)
      #pragma unroll
      for (int ni = 0; ni < 4; ni++)
        acc[mi][ni] = __builtin_amdgcn_mfma_f32_16x16x32_bf16(av[mi], bv[ni], acc[mi][ni], 0, 0, 0);
    __syncthreads();
  }

  #pragma unroll
  for (int mi = 0; mi < 4; mi++){
    #pragma unroll
    for (int ni = 0; ni < 4; ni++){
      int row = row0 + wm*64 + mi*16 + g*4;
      int col = col0 + wn*64 + ni*16 + fr;
      float bb = bfb[col];
      #pragma unroll
      for (int r = 0; r < 4; r++)
        out[(long)(row + r) * EE + col] = acc[mi][ni][r] + bb;
    }
  }
}

// ---------------- flash attention v13: R7 math, 2 blocks/CU ----------------
// LDS = Ks 32KB (single) + Vs 32KB (single) = 64KB -> 2 blocks/CU (4 waves/SIMD).
// After B1 (all QK reads done) Ks is dead until restage -> its 32KB doubles as the
// fp32 Sx exchange buffer. 4 barriers/tile; CH=12 -> 408 blocks, makespan 12 tiles
// (vs R12: 1 block/CU, 2 barriers, 22 tiles, 123us). Math byte-identical to R7.
#define QB 128
#define TB 32

__global__ __launch_bounds__(512, 4) void k_flash13(
    const unsigned short* __restrict__ Qg, const unsigned short* __restrict__ Kg,
    const unsigned short* __restrict__ Vtg,
    unsigned short* __restrict__ Opart, float* __restrict__ mlg,
    const int* __restrict__ maskedp)
{
  __shared__ unsigned short Ks[TB * HH];      // 32KB; becomes Sx after QK's B1
  __shared__ unsigned short Vs[HH * TB];      // 32KB
  float2* Sx = (float2*)Ks;                   // [rg][dh][i][lane] = ((rg*2+dh)*8+i)*64+lane

  const int bid = blockIdx.x;
  const int bn = bid & 7;                     // XCD pinning
  const int u = bid >> 3;                     // [0, 51)
  const int masked = *maskedp;
  int qi, c, pfx;
  if (masked){
    qi = -1; c = 0; pfx = 0;
    int cnt = 0;
    #pragma unroll 1
    for (int q = 0; q < 16; q++){
      int nch = (4*q + 15) / 12;              // ceil((4q+4)/12); sum = 51
      if (qi < 0 && u >= cnt && u < cnt + nch){ qi = q; c = u - cnt; pfx = cnt; }
      cnt += nch;
    }
    if (qi < 0) return;
  } else {
    if (u >= 32) return;
    qi = u >> 1; c = u & 1; pfx = qi * 2;
  }
  const int n  = masked ? 4*qi + 4 : 64;
  const int CH = masked ? 12 : 32;
  const int t0 = c * CH;
  const int t1 = min(n, t0 + CH);

  const long base = (long)bn * SS * HH;
  const unsigned short* Qp = Qg + base;
  const unsigned short* Kp = Kg + base;
  const unsigned short* Vp = Vtg + base;

  const int tid = threadIdx.x, lane = tid & 63, w = tid >> 6;
  const int ln = lane & 31, hi = lane >> 5;
  const int rg = w & 3, dh = w >> 2;
  const int q0 = qi * QB;
  const int myq = q0 + rg * 32 + ln;          // this lane's softmax row

  // Q as B-frags for this wave's K-half
  short8 Qr[16];
  {
    const unsigned short* qrow = Qp + (long)myq * HH + dh * 256 + hi * 8;
    #pragma unroll
    for (int ks = 0; ks < 16; ks++) Qr[ks] = *(const short8*)(qrow + ks * 16);
  }

  f32x16 oa[8];
  #pragma unroll
  for (int i = 0; i < 8; i++)
    #pragma unroll
    for (int r = 0; r < 16; r++) oa[i][r] = 0.f;
  float m_r = -1e30f, l_r = 0.f;

  auto stageK = [&](int t){                   // waves 0-3: K tile (32 rows x 64 chunks)
    if (w < 4){
      #pragma unroll
      for (int i = 0; i < 8; i++){
        const int sbase = w * 512 + i * 64;
        const int slot = sbase + lane;
        int row = slot >> 6, ch = slot & 63;
        int sc_ = ch ^ (row & 7);
        gload16(Kp + (long)(t * TB + row) * HH + sc_ * 8, &Ks[sbase * 8]);
      }
    }
  };
  auto stageV = [&](int t){                   // waves 4-7: V^T tile (512 rows x 4 chunks)
    if (w >= 4){
      #pragma unroll
      for (int i = 0; i < 8; i++){
        const int sbase = (w - 4) * 512 + i * 64;
        const int slot = sbase + lane;
        int row = slot >> 2, ch = slot & 3;
        int sc_ = ch ^ ((row >> 1) & 3);
        gload16(Vp + (long)row * SS + t * TB + sc_ * 8, &Vs[sbase * 8]);
      }
    }
  };

  stageK(t0); stageV(t0);
  __syncthreads();                            // B0: tiles visible

  for (int t = t0; t < t1; ++t){
    // ---- QK^T (swapped): partial S^T[t][q] over this wave's K-half ----
    f32x16 sa;
    #pragma unroll
    for (int r = 0; r < 16; r++) sa[r] = 0.f;
    #pragma unroll
    for (int ks = 0; ks < 16; ks++){
      int ch = (dh * 32 + ks * 2 + hi) ^ (ln & 7);
      short8 kf = *(const short8*)&Ks[ln * HH + ch * 8];
      sa = __builtin_amdgcn_mfma_f32_32x32x16_bf16(kf, Qr[ks], sa, 0, 0, 0);
    }

    __syncthreads();                          // B1: all QK reads done -> Ks reusable as Sx

    // ---- publish fp32 partials into Sx (overlays Ks) ----
    #pragma unroll
    for (int i = 0; i < 8; i++)
      Sx[((rg * 2 + dh) * 8 + i) * 64 + lane] = make_float2(sa[2*i], sa[2*i+1]);

    __syncthreads();                          // B1': Sx visible

    // ---- sum halves ----
    float p[16];
    #pragma unroll
    for (int i = 0; i < 8; i++){
      float2 o = Sx[((rg * 2 + (dh ^ 1)) * 8 + i) * 64 + lane];
      p[2*i]   = sa[2*i]   + o.x;
      p[2*i+1] = sa[2*i+1] + o.y;
    }

    // ---- mask ----
    if (masked && (t * TB + TB - 1 > myq)){
      #pragma unroll
      for (int r = 0; r < 16; r++){
        int tl = (r & 3) + 8 * (r >> 2) + 4 * hi;
        if (t * TB + tl > myq) p[r] = -1e30f;
      }
    }

    // ---- lane-local softmax (row q = lane&31) ----
    float mx = p[0];
    #pragma unroll
    for (int r = 1; r < 16; r++) mx = fmaxf(mx, p[r]);
    mx = fmaxf(mx, __shfl_xor(mx, 32, 64));
    if (__any(mx > m_r + 8.f)){
      float mn = fmaxf(m_r, mx);
      float alpha = __expf(m_r - mn);
      m_r = mn; l_r *= alpha;
      #pragma unroll
      for (int r = 0; r < 16; r++){
        float al = __shfl(alpha, (r & 3) + 8 * (r >> 2) + 4 * hi, 64);
        #pragma unroll
        for (int i = 0; i < 8; i++) oa[i][r] *= al;
      }
    }
    float ps = 0.f;
    #pragma unroll
    for (int r = 0; r < 16; r++){ float pe = __expf(p[r] - m_r); p[r] = pe; ps += pe; }
    ps += __shfl_xor(ps, 32, 64);
    l_r += ps;

    // ---- T12 P-pack: build PV A-frags in-register ----
    unsigned W[8], R[8];
    #pragma unroll
    for (int i = 0; i < 8; i++) W[i] = cvtpk(p[2*i], p[2*i+1]);
    #pragma unroll
    for (int i = 0; i < 8; i++) R[i] = __shfl_xor(W[i], 32, 64);
    union { unsigned u[4]; short8 s; } fa0, fa1;
    fa0.u[0] = hi ? R[2] : W[0];  fa0.u[1] = hi ? R[3] : W[1];
    fa0.u[2] = hi ? W[2] : R[0];  fa0.u[3] = hi ? W[3] : R[1];
    fa1.u[0] = hi ? R[6] : W[4];  fa1.u[1] = hi ? R[7] : W[5];
    fa1.u[2] = hi ? W[6] : R[4];  fa1.u[3] = hi ? W[7] : R[5];

    // ---- PV: O[32 q][256 h] += P[32 q][32 t] * Vt (this wave's D-half) ----
    #pragma unroll
    for (int cf = 0; cf < 8; cf++){
      int h = dh * 256 + cf * 32 + ln;
      int sw = (h >> 1) & 3;
      short8 v0 = *(const short8*)&Vs[h * TB + ((hi     ^ sw) * 8)];
      oa[cf] = __builtin_amdgcn_mfma_f32_32x32x16_bf16(fa0.s, v0, oa[cf], 0, 0, 0);
      short8 v1 = *(const short8*)&Vs[h * TB + (((2+hi) ^ sw) * 8)];
      oa[cf] = __builtin_amdgcn_mfma_f32_32x32x16_bf16(fa1.s, v1, oa[cf], 0, 0, 0);
    }

    __syncthreads();                          // B2: PV + Sx reads done -> buffers writable

    if (t + 1 < t1){
      stageK(t + 1); stageV(t + 1);
      __syncthreads();                        // B0': next tiles visible (drains vmcnt)
    }
  }

  // ---- write bf16 partial O + (m,l) ----
  const long slot = (long)bn * 51 + pfx + c;
  unsigned short* dst = Opart + slot * (QB * HH);
  #pragma unroll
  for (int cf = 0; cf < 8; cf++){
    int col = dh * 256 + cf * 32 + ln;
    #pragma unroll
    for (int r = 0; r < 16; r++){
      int row = rg * 32 + (r & 3) + 8 * (r >> 2) + 4 * hi;
      dst[row * HH + col] = f2bf(oa[cf][r]);
    }
  }
  if (w < 4 && hi == 0){
    mlg[slot * 256 + rg * 32 + ln]       = m_r;
    mlg[slot * 256 + 128 + rg * 32 + ln] = l_r;
  }
}

// ---------------- combine partials -> O (bf16), prefix slots, NC<=6 ----------------
__global__ __launch_bounds__(256) void k_combine(
    const unsigned short* __restrict__ Opart, const float* __restrict__ mlg,
    unsigned short* __restrict__ O, const int* __restrict__ maskedp)
{
  __shared__ float wl[128][6];
  const int gq = blockIdx.x;
  const int bn = gq & 7, qi = gq >> 3;
  const int b = bn >> 1, n = bn & 1;
  const int masked = *maskedp;
  int NC, pfx;
  if (masked){
    NC = (4*qi + 15) / 12;
    pfx = 0;
    #pragma unroll 1
    for (int q = 0; q < qi; q++) pfx += (4*q + 15) / 12;
  } else { NC = 2; pfx = qi * 2; }
  const long slotbase = (long)bn * 51 + pfx;
  const int tid = threadIdx.x;

  if (tid < 128){
    float mc[6], lc[6];
    float M = -1e30f;
    for (int c = 0; c < NC; c++){
      mc[c] = mlg[(slotbase + c) * 256 + tid];
      lc[c] = mlg[(slotbase + c) * 256 + 128 + tid];
      M = fmaxf(M, mc[c]);
    }
    float L = 0.f;
    for (int c = 0; c < NC; c++){
      float wc = __expf(mc[c] - M);
      mc[c] = wc;
      L += lc[c] * wc;
    }
    float inv = 1.f / L;
    #pragma unroll
    for (int c = 0; c < 6; c++) wl[tid][c] = (c < NC) ? mc[c] * inv : 0.f;
  }
  __syncthreads();

  for (int it = 0; it < 32; it++){
    int idx = it * 256 + tid;                 // 128 rows x 64 chunks
    int row = idx >> 6, cv = idx & 63;
    float acc[8] = {0.f,0.f,0.f,0.f,0.f,0.f,0.f,0.f};
    for (int c = 0; c < NC; c++){
      float wc = wl[row][c];
      short8 v = *(const short8*)&Opart[(slotbase + c) * (QB * HH) + row * HH + cv * 8];
      #pragma unroll
      for (int j = 0; j < 8; j++){
        float f = __uint_as_float((unsigned)(unsigned short)v[j] << 16);
        acc[j] += f * wc;
      }
    }
    union { unsigned short u[8]; uint4 q; } rr;
    #pragma unroll
    for (int j = 0; j < 8; j++) rr.u[j] = f2bf(acc[j]);
    long dstoff = ((long)b * SS + qi * QB + row) * EE + n * HH + cv * 8;
    *(uint4*)&O[dstoff] = rr.q;
  }
}

// ---------------- host launch ----------------
extern "C" void kernel_launch(void* const* d_in, const int* in_sizes, int n_in,
                              void* d_out, int out_size, void* d_ws, size_t ws_size,
                              hipStream_t stream)
{
  const float* x   = (const float*)d_in[0];
  const float* Wq  = (const float*)d_in[1];
  const float* bq  = (const float*)d_in[2];
  const float* Wk  = (const float*)d_in[3];
  const float* bk  = (const float*)d_in[4];
  const float* Wv  = (const float*)d_in[5];
  const float* bv  = (const float*)d_in[6];
  const float* Wf  = (const float*)d_in[7];
  const float* bf_ = (const float*)d_in[8];
  const int* masked = (const int*)d_in[9];

  char* p = (char*)d_ws;
  const long TEN = (long)BB * SS * EE * 2;                 // 16 MiB per bf16 tensor
  unsigned short* xb  = (unsigned short*)p; p += TEN;
  unsigned short* Qb  = (unsigned short*)p; p += TEN;
  unsigned short* Kb  = (unsigned short*)p; p += TEN;
  unsigned short* Vt  = (unsigned short*)p; p += TEN;      // V^T, written directly by k_qkvall
  unsigned short* Ob  = (unsigned short*)p; p += TEN;      // combined O
  unsigned short* wqb = (unsigned short*)p; p += 2L * HH * HH * 2;
  unsigned short* wkb = (unsigned short*)p; p += 2L * HH * HH * 2;
  unsigned short* wvb = (unsigned short*)p; p += 2L * HH * HH * 2;
  unsigned short* wfb = (unsigned short*)p; p += (long)EE * EE * 2;
  unsigned short* Opart = (unsigned short*)p; p += 408L * QB * HH * 2;   // 53.5 MB (8*51 slots)
  float* mlg = (float*)p; p += 408L * 256 * 4;                           // 0.4 MB

  k_cvt_all<<<dim3(2048), 256, 0, stream>>>(x, Wq, Wk, Wv, Wf, xb, wqb, wkb, wvb, wfb);
  k_qkvall <<<dim3(SS / 128, HH / 128, 24), 256, 0, stream>>>(xb, wqb, wkb, wvb,
                                                              bq, bk, bv, Qb, Kb, Vt);
  k_flash13<<<dim3(408), 512, 0, stream>>>(Qb, Kb, Vt, Opart, mlg, masked);
  k_combine<<<dim3(128), 256, 0, stream>>>(Opart, mlg, Ob, masked);
  k_outproj<<<dim3((BB * SS) / 128, EE / 128, 1), 256, 0, stream>>>(Ob, wfb, bf_, (float*)d_out);
}

// Round 14
// 221.145 us; speedup vs baseline: 4.7094x; 4.7094x over previous
//
#include <hip/hip_runtime.h>
#include <hip/hip_bf16.h>

#define BB 4
#define SS 2048
#define EE 1024
#define HH 512

typedef __attribute__((ext_vector_type(8))) short short8;
typedef __attribute__((ext_vector_type(4))) float f32x4;
typedef __attribute__((ext_vector_type(16))) float f32x16;
typedef __attribute__((ext_vector_type(4))) unsigned short us4;

static __device__ __forceinline__ unsigned short f2bf(float x){
  unsigned u = __float_as_uint(x);
  u += 0x7fffu + ((u >> 16) & 1u);
  return (unsigned short)(u >> 16);
}

static __device__ __forceinline__ unsigned cvtpk(float lo, float hi){
  unsigned d;
  asm("v_cvt_pk_bf16_f32 %0, %1, %2" : "=v"(d) : "v"(lo), "v"(hi));
  return d;
}

static __device__ __forceinline__ void gload16(const void* g, void* l){
  __builtin_amdgcn_global_load_lds((const __attribute__((address_space(1))) void*)g,
                                   (__attribute__((address_space(3))) void*)l, 16, 0, 0);
}

// ---------------- fused fp32 -> bf16 conversion for all 5 tensors ----------------
__global__ void k_cvt_all(const float* __restrict__ x,  const float* __restrict__ wq,
                          const float* __restrict__ wk, const float* __restrict__ wv,
                          const float* __restrict__ wf,
                          unsigned short* __restrict__ xb,  unsigned short* __restrict__ wqb,
                          unsigned short* __restrict__ wkb, unsigned short* __restrict__ wvb,
                          unsigned short* __restrict__ wfb){
  const int N0 = 1048576;            // x: 4*2048*1024/8
  const int N1 = N0 + 65536;         // wq
  const int N2 = N1 + 65536;         // wk
  const int N3 = N2 + 65536;         // wv
  const int N4 = N3 + 131072;        // wf
  int idx = blockIdx.x * blockDim.x + threadIdx.x;
  int stride = gridDim.x * blockDim.x;
  for (int i = idx; i < N4; i += stride){
    const float* src; unsigned short* dst; int j;
    if (i < N0){ src = x;  dst = xb;  j = i; }
    else if (i < N1){ src = wq; dst = wqb; j = i - N0; }
    else if (i < N2){ src = wk; dst = wkb; j = i - N1; }
    else if (i < N3){ src = wv; dst = wvb; j = i - N2; }
    else            { src = wf; dst = wfb; j = i - N3; }
    const float4* p = (const float4*)src + (long)j * 2;
    float4 a = p[0], b = p[1];
    union { unsigned short u[8]; uint4 v; } r;
    r.u[0]=f2bf(a.x); r.u[1]=f2bf(a.y); r.u[2]=f2bf(a.z); r.u[3]=f2bf(a.w);
    r.u[4]=f2bf(b.x); r.u[5]=f2bf(b.y); r.u[6]=f2bf(b.z); r.u[7]=f2bf(b.w);
    ((uint4*)dst)[j] = r.v;
  }
}

#define GBK 32

// ---------------- merged QKV GEMM (Q, K row-major; V transposed epilogue) ----------
__global__ __launch_bounds__(256, 2) void k_qkvall(
    const unsigned short* __restrict__ xb,
    const unsigned short* __restrict__ wq, const unsigned short* __restrict__ wk,
    const unsigned short* __restrict__ wv,
    const float* __restrict__ bq, const float* __restrict__ bk, const float* __restrict__ bv,
    unsigned short* __restrict__ Q, unsigned short* __restrict__ K,
    unsigned short* __restrict__ Vt)
{
  __shared__ union {
    struct { unsigned short As[2][128 * GBK]; unsigned short Bs[2][128 * GBK]; } g;
    unsigned short Ct[128][136];
  } sm;

  const int z = blockIdx.z;
  const int which = z >> 3, bn = z & 7, b = bn >> 1, n = bn & 1;
  const unsigned short* W; const float* bias; unsigned short* out;
  float os = 1.f; int ldc;
  if (which == 0){ W = wq + n*HH*HH; bias = bq + n*HH; out = Q  + (long)bn*SS*HH;
                   os = 0.044194173824159216f; ldc = HH; }        // fold 1/sqrt(512) into Q
  else if (which == 1){ W = wk + n*HH*HH; bias = bk + n*HH; out = K + (long)bn*SS*HH; ldc = HH; }
  else { W = wv + n*HH*HH; bias = bv + n*HH; out = Vt + (long)bn*SS*HH; ldc = SS; }
  const unsigned short* A = xb + (long)b * SS * EE + n * HH;
  const int row0 = blockIdx.x * 128, col0 = blockIdx.y * 128;

  const int tid = threadIdx.x, lane = tid & 63, w = tid >> 6;
  const int wm = w >> 1, wn = w & 1;
  const int fr = lane & 15, g = lane >> 4;

  f32x4 acc[4][4];
  #pragma unroll
  for (int i = 0; i < 4; i++)
    #pragma unroll
    for (int j = 0; j < 4; j++){ acc[i][j][0]=0.f; acc[i][j][1]=0.f; acc[i][j][2]=0.f; acc[i][j][3]=0.f; }

  const unsigned short* gAsrc[2]; const unsigned short* gBsrc[2];
  unsigned ldsOff[2];
  #pragma unroll
  for (int i = 0; i < 2; i++){
    int slot = w*128 + i*64 + lane;
    int row = slot >> 2, ch = slot & 3;
    int sc_ = ch ^ ((row >> 1) & 3);
    gAsrc[i] = A + (long)(row0 + row) * EE + sc_ * 8;
    gBsrc[i] = W + (long)(col0 + row) * HH + sc_ * 8;
    ldsOff[i] = (unsigned)((w*128 + i*64) * 8);
  }

  unsigned aoff[4], boff[4];
  #pragma unroll
  for (int mi = 0; mi < 4; mi++){
    int row = wm*64 + mi*16 + fr;
    aoff[mi] = row * GBK + ((g ^ ((row >> 1) & 3)) * 8);
  }
  #pragma unroll
  for (int ni = 0; ni < 4; ni++){
    int row = wn*64 + ni*16 + fr;
    boff[ni] = row * GBK + ((g ^ ((row >> 1) & 3)) * 8);
  }

  const int KT = HH / GBK;                      // 16
  #pragma unroll
  for (int i = 0; i < 2; i++) gload16(gAsrc[i], &sm.g.As[0][ldsOff[i]]);
  #pragma unroll
  for (int i = 0; i < 2; i++) gload16(gBsrc[i], &sm.g.Bs[0][ldsOff[i]]);
  __syncthreads();

  for (int kt = 0; kt < KT; ++kt){
    const int cur = kt & 1;
    if (kt + 1 < KT){
      #pragma unroll
      for (int i = 0; i < 2; i++) gload16(gAsrc[i] + (kt+1)*GBK, &sm.g.As[cur^1][ldsOff[i]]);
      #pragma unroll
      for (int i = 0; i < 2; i++) gload16(gBsrc[i] + (kt+1)*GBK, &sm.g.Bs[cur^1][ldsOff[i]]);
    }
    short8 av[4], bv[4];
    #pragma unroll
    for (int mi = 0; mi < 4; mi++) av[mi] = *(const short8*)&sm.g.As[cur][aoff[mi]];
    #pragma unroll
    for (int ni = 0; ni < 4; ni++) bv[ni] = *(const short8*)&sm.g.Bs[cur][boff[ni]];
    #pragma unroll
    for (int mi = 0; mi < 4; mi++)
      #pragma unroll
      for (int ni = 0; ni < 4; ni++)
        acc[mi][ni] = __builtin_amdgcn_mfma_f32_16x16x32_bf16(av[mi], bv[ni], acc[mi][ni], 0, 0, 0);
    __syncthreads();                            // last iter: As/Bs dead after this
  }

  if (which == 2){
    // transposed epilogue: Ct overlays As/Bs (safe: all waves past final barrier)
    #pragma unroll
    for (int mi = 0; mi < 4; mi++){
      #pragma unroll
      for (int ni = 0; ni < 4; ni++){
        int rowb = wm*64 + mi*16 + g*4;         // s-local
        int col  = wn*64 + ni*16 + fr;          // o-local
        float bb = bias[col0 + col];
        us4 pk;
        #pragma unroll
        for (int r = 0; r < 4; r++) pk[r] = f2bf((acc[mi][ni][r] + bb) * os);
        *(us4*)&sm.Ct[col][rowb] = pk;
      }
    }
    __syncthreads();
    #pragma unroll
    for (int it = 0; it < 8; it++){
      int idx2 = it * 256 + tid;                // 128 o x 16 s-chunks
      int o = idx2 >> 4, sch = idx2 & 15;
      uint4 v = *(const uint4*)&sm.Ct[o][sch * 8];
      *(uint4*)&out[(long)(col0 + o) * ldc + row0 + sch * 8] = v;
    }
  } else {
    #pragma unroll
    for (int mi = 0; mi < 4; mi++){
      #pragma unroll
      for (int ni = 0; ni < 4; ni++){
        int row = row0 + wm*64 + mi*16 + g*4;
        int col = col0 + wn*64 + ni*16 + fr;
        float bb = bias[col];
        #pragma unroll
        for (int r = 0; r < 4; r++){
          float v = (acc[mi][ni][r] + bb) * os;
          out[(long)(row + r) * ldc + col] = f2bf(v);
        }
      }
    }
  }
}

// ---------------- output projection GEMM (f32 out), R12-exact ----------------
__global__ __launch_bounds__(256, 2) void k_outproj(
    const unsigned short* __restrict__ O, const unsigned short* __restrict__ wf,
    const float* __restrict__ bfb, float* __restrict__ out)
{
  __shared__ unsigned short As[2][128 * GBK];
  __shared__ unsigned short Bs[2][128 * GBK];
  const int tid = threadIdx.x, lane = tid & 63, w = tid >> 6;
  const int wm = w >> 1, wn = w & 1;
  const int fr = lane & 15, g = lane >> 4;
  const int row0 = blockIdx.x * 128, col0 = blockIdx.y * 128;

  f32x4 acc[4][4];
  #pragma unroll
  for (int i = 0; i < 4; i++)
    #pragma unroll
    for (int j = 0; j < 4; j++){ acc[i][j][0]=0.f; acc[i][j][1]=0.f; acc[i][j][2]=0.f; acc[i][j][3]=0.f; }

  const unsigned short* gAsrc[2]; const unsigned short* gBsrc[2];
  unsigned ldsOff[2];
  #pragma unroll
  for (int i = 0; i < 2; i++){
    int slot = w*128 + i*64 + lane;
    int row = slot >> 2, ch = slot & 3;
    int sc_ = ch ^ ((row >> 1) & 3);
    gAsrc[i] = O  + (long)(row0 + row) * EE + sc_ * 8;
    gBsrc[i] = wf + (long)(col0 + row) * EE + sc_ * 8;
    ldsOff[i] = (unsigned)((w*128 + i*64) * 8);
  }

  unsigned aoff[4], boff[4];
  #pragma unroll
  for (int mi = 0; mi < 4; mi++){
    int row = wm*64 + mi*16 + fr;
    aoff[mi] = row * GBK + ((g ^ ((row >> 1) & 3)) * 8);
  }
  #pragma unroll
  for (int ni = 0; ni < 4; ni++){
    int row = wn*64 + ni*16 + fr;
    boff[ni] = row * GBK + ((g ^ ((row >> 1) & 3)) * 8);
  }

  const int KT = EE / GBK;
  #pragma unroll
  for (int i = 0; i < 2; i++) gload16(gAsrc[i], &As[0][ldsOff[i]]);
  #pragma unroll
  for (int i = 0; i < 2; i++) gload16(gBsrc[i], &Bs[0][ldsOff[i]]);
  __syncthreads();

  for (int kt = 0; kt < KT; ++kt){
    const int cur = kt & 1;
    if (kt + 1 < KT){
      #pragma unroll
      for (int i = 0; i < 2; i++) gload16(gAsrc[i] + (kt+1)*GBK, &As[cur^1][ldsOff[i]]);
      #pragma unroll
      for (int i = 0; i < 2; i++) gload16(gBsrc[i] + (kt+1)*GBK, &Bs[cur^1][ldsOff[i]]);
    }
    short8 av[4], bv[4];
    #pragma unroll
    for (int mi = 0; mi < 4; mi++) av[mi] = *(const short8*)&As[cur][aoff[mi]];
    #pragma unroll
    for (int ni = 0; ni < 4; ni++) bv[ni] = *(const short8*)&Bs[cur][boff[ni]];
    #pragma unroll
    for (int mi = 0; mi < 4; mi++)
      #pragma unroll
      for (int ni = 0; ni < 4; ni++)
        acc[mi][ni] = __builtin_amdgcn_mfma_f32_16x16x32_bf16(av[mi], bv[ni], acc[mi][ni], 0, 0, 0);
    __syncthreads();
  }

  #pragma unroll
  for (int mi = 0; mi < 4; mi++){
    #pragma unroll
    for (int ni = 0; ni < 4; ni++){
      int row = row0 + wm*64 + mi*16 + g*4;
      int col = col0 + wn*64 + ni*16 + fr;
      float bb = bfb[col];
      #pragma unroll
      for (int r = 0; r < 4; r++)
        out[(long)(row + r) * EE + col] = acc[mi][ni][r] + bb;
    }
  }
}

// ---------------- flash attention v14 == R12/R7-exact loop + NC=1 direct write ----
// Register-bound plateau: 128 VGPR + 128 AGPR = 256 unified = exactly 2 waves/SIMD.
// DO NOT: reorder staging/barriers (R8=154, R9=135, this=122.6), raise launch_bounds
// min-waves (R13: VGPR capped 64 -> 1.75GB scratch spill, 990us), or add arch VGPRs.
// New vs R12: masked single-chunk blocks (qi<=4) write normalized O directly to Ob.
#define QB 128
#define TB 32

__global__ __launch_bounds__(512, 1) void k_flash14(
    const unsigned short* __restrict__ Qg, const unsigned short* __restrict__ Kg,
    const unsigned short* __restrict__ Vtg,
    unsigned short* __restrict__ Opart, float* __restrict__ mlg,
    unsigned short* __restrict__ Ob, const int* __restrict__ maskedp)
{
  __shared__ unsigned short Ks[2][TB * HH];   // 64KB: [32 t][512 k], chunk swz: ch ^ (t&7)
  __shared__ unsigned short Vs[HH * TB];      // 32KB: [512 h][32 t], chunk swz: ch ^ ((h>>1)&3)
  __shared__ float2 Sx[4][2][8][64];          // 32KB: fp32 partial-score exchange

  const int bid = blockIdx.x;
  const int bn = bid & 7;                     // XCD pinning
  const int u = bid >> 3;
  const int masked = *maskedp;
  int qi, c;
  if (masked){
    qi = -1; c = 0;
    int cnt = 0;
    #pragma unroll 1
    for (int q = 0; q < 16; q++){
      int nch = (4*q + 25) / 22;              // ceil((4q+4)/22); sum = 32 (optimal, 256 blocks)
      if (qi < 0 && u >= cnt && u < cnt + nch){ qi = q; c = u - cnt; }
      cnt += nch;
    }
    if (qi < 0) return;
  } else { qi = u >> 1; c = u & 1; }
  const int n  = masked ? 4*qi + 4 : 64;
  const int CH = masked ? 22 : 32;
  const int t0 = c * CH;
  const int t1 = min(n, t0 + CH);
  const bool single = (t1 - t0) == n;         // this block covers ALL tiles of (bn,qi)

  const long base = (long)bn * SS * HH;
  const unsigned short* Qp = Qg + base;
  const unsigned short* Kp = Kg + base;
  const unsigned short* Vp = Vtg + base;

  const int tid = threadIdx.x, lane = tid & 63, w = tid >> 6;
  const int ln = lane & 31, hi = lane >> 5;
  const int rg = w & 3, dh = w >> 2;
  const int q0 = qi * QB;
  const int myq = q0 + rg * 32 + ln;          // this lane's softmax row

  // Q as B-frags for this wave's K-half
  short8 Qr[16];
  {
    const unsigned short* qrow = Qp + (long)myq * HH + dh * 256 + hi * 8;
    #pragma unroll
    for (int ks = 0; ks < 16; ks++) Qr[ks] = *(const short8*)(qrow + ks * 16);
  }

  f32x16 oa[8];
  #pragma unroll
  for (int i = 0; i < 8; i++)
    #pragma unroll
    for (int r = 0; r < 16; r++) oa[i][r] = 0.f;
  float m_r = -1e30f, l_r = 0.f;

  auto stageK = [&](int buf, int t){          // waves 0-3: K tile (32 rows x 64 chunks)
    if (w < 4){
      #pragma unroll
      for (int i = 0; i < 8; i++){
        const int sbase = w * 512 + i * 64;
        const int slot = sbase + lane;
        int row = slot >> 6, ch = slot & 63;
        int sc_ = ch ^ (row & 7);
        gload16(Kp + (long)(t * TB + row) * HH + sc_ * 8, &Ks[buf][sbase * 8]);
      }
    }
  };
  auto stageV = [&](int t){                   // waves 4-7: V^T tile (512 rows x 4 chunks)
    if (w >= 4){
      #pragma unroll
      for (int i = 0; i < 8; i++){
        const int sbase = (w - 4) * 512 + i * 64;
        const int slot = sbase + lane;
        int row = slot >> 2, ch = slot & 3;
        int sc_ = ch ^ ((row >> 1) & 3);
        gload16(Vp + (long)row * SS + t * TB + sc_ * 8, &Vs[sbase * 8]);
      }
    }
  };

  stageK(0, t0);
  stageV(t0);
  __syncthreads();

  for (int t = t0; t < t1; ++t){
    const int cur = (t - t0) & 1;
    if (t > t0)     stageV(t);                // Vs free (PV(t-1) done); drained at B1
    if (t + 1 < t1) stageK(cur ^ 1, t + 1);   // drained at B1 (issued early, QK as cover)

    // ---- QK^T (swapped): partial S^T[t][q] over this wave's K-half ----
    f32x16 sa;
    #pragma unroll
    for (int r = 0; r < 16; r++) sa[r] = 0.f;
    #pragma unroll
    for (int ks = 0; ks < 16; ks++){
      int ch = (dh * 32 + ks * 2 + hi) ^ (ln & 7);
      short8 kf = *(const short8*)&Ks[cur][ln * HH + ch * 8];
      sa = __builtin_amdgcn_mfma_f32_32x32x16_bf16(kf, Qr[ks], sa, 0, 0, 0);
    }

    // ---- publish fp32 partials ----
    #pragma unroll
    for (int i = 0; i < 8; i++)
      Sx[rg][dh][i][lane] = make_float2(sa[2*i], sa[2*i+1]);

    __syncthreads();                          // B1: Sx + V(t) visible

    // ---- sum halves ----
    float p[16];
    #pragma unroll
    for (int i = 0; i < 8; i++){
      float2 o = Sx[rg][dh ^ 1][i][lane];
      p[2*i]   = sa[2*i]   + o.x;
      p[2*i+1] = sa[2*i+1] + o.y;
    }

    // ---- mask ----
    if (masked && (t * TB + TB - 1 > myq)){
      #pragma unroll
      for (int r = 0; r < 16; r++){
        int tl = (r & 3) + 8 * (r >> 2) + 4 * hi;
        if (t * TB + tl > myq) p[r] = -1e30f;
      }
    }

    // ---- lane-local softmax (row q = lane&31) ----
    float mx = p[0];
    #pragma unroll
    for (int r = 1; r < 16; r++) mx = fmaxf(mx, p[r]);
    mx = fmaxf(mx, __shfl_xor(mx, 32, 64));
    if (__any(mx > m_r + 8.f)){
      float mn = fmaxf(m_r, mx);
      float alpha = __expf(m_r - mn);
      m_r = mn; l_r *= alpha;
      #pragma unroll
      for (int r = 0; r < 16; r++){
        float al = __shfl(alpha, (r & 3) + 8 * (r >> 2) + 4 * hi, 64);
        #pragma unroll
        for (int i = 0; i < 8; i++) oa[i][r] *= al;
      }
    }
    float ps = 0.f;
    #pragma unroll
    for (int r = 0; r < 16; r++){ float pe = __expf(p[r] - m_r); p[r] = pe; ps += pe; }
    ps += __shfl_xor(ps, 32, 64);
    l_r += ps;

    // ---- T12 P-pack: build PV A-frags in-register ----
    unsigned W[8], R[8];
    #pragma unroll
    for (int i = 0; i < 8; i++) W[i] = cvtpk(p[2*i], p[2*i+1]);
    #pragma unroll
    for (int i = 0; i < 8; i++) R[i] = __shfl_xor(W[i], 32, 64);
    union { unsigned u[4]; short8 s; } fa0, fa1;
    fa0.u[0] = hi ? R[2] : W[0];  fa0.u[1] = hi ? R[3] : W[1];
    fa0.u[2] = hi ? W[2] : R[0];  fa0.u[3] = hi ? W[3] : R[1];
    fa1.u[0] = hi ? R[6] : W[4];  fa1.u[1] = hi ? R[7] : W[5];
    fa1.u[2] = hi ? W[6] : R[4];  fa1.u[3] = hi ? W[7] : R[5];

    // ---- PV: O[32 q][256 h] += P[32 q][32 t] * Vt (this wave's D-half) ----
    #pragma unroll
    for (int cf = 0; cf < 8; cf++){
      int h = dh * 256 + cf * 32 + ln;
      int sw = (h >> 1) & 3;
      short8 v0 = *(const short8*)&Vs[h * TB + ((hi     ^ sw) * 8)];
      oa[cf] = __builtin_amdgcn_mfma_f32_32x32x16_bf16(fa0.s, v0, oa[cf], 0, 0, 0);
      short8 v1 = *(const short8*)&Vs[h * TB + (((2+hi) ^ sw) * 8)];
      oa[cf] = __builtin_amdgcn_mfma_f32_32x32x16_bf16(fa1.s, v1, oa[cf], 0, 0, 0);
    }

    __syncthreads();                          // B2: Vs/Sx free for next iter
  }

  if (single){
    // ---- direct normalized write to Ob (skip Opart/mlg + combine for this (bn,qi)) ----
    const int b = bn >> 1, nn = bn & 1;
    float inv = 1.f / l_r;                    // keyed to row myq (lane&31)
    unsigned short* dst = Ob + ((long)b * SS + q0 + rg * 32) * EE + nn * HH;
    #pragma unroll
    for (int cf = 0; cf < 8; cf++){
      int col = dh * 256 + cf * 32 + ln;
      #pragma unroll
      for (int r = 0; r < 16; r++){
        int crow = (r & 3) + 8 * (r >> 2) + 4 * hi;
        float invr = __shfl(inv, crow, 64);
        dst[(long)crow * EE + col] = f2bf(oa[cf][r] * invr);
      }
    }
  } else {
    // ---- write bf16 partial O + (m,l) ----
    const long slot = (long)(bn * 16 + qi) * 3 + c;
    unsigned short* dst = Opart + slot * (QB * HH);
    #pragma unroll
    for (int cf = 0; cf < 8; cf++){
      int col = dh * 256 + cf * 32 + ln;
      #pragma unroll
      for (int r = 0; r < 16; r++){
        int row = rg * 32 + (r & 3) + 8 * (r >> 2) + 4 * hi;
        dst[row * HH + col] = f2bf(oa[cf][r]);
      }
    }
    if (w < 4 && hi == 0){
      mlg[slot * 256 + rg * 32 + ln]       = m_r;
      mlg[slot * 256 + 128 + rg * 32 + ln] = l_r;
    }
  }
}

// ---------------- combine partials -> O (bf16); skips single-chunk (bn,qi) ----------
__global__ __launch_bounds__(256) void k_combine(
    const unsigned short* __restrict__ Opart, const float* __restrict__ mlg,
    unsigned short* __restrict__ O, const int* __restrict__ maskedp)
{
  __shared__ float wl[128][3];
  const int gq = blockIdx.x;
  const int bn = gq & 7, qi = gq >> 3;
  const int b = bn >> 1, n = bn & 1;
  const int masked = *maskedp;
  const int NC = masked ? (4*qi + 25) / 22 : 2;
  if (masked && NC == 1) return;              // flash wrote Ob directly
  const long slotbase = (long)(bn * 16 + qi) * 3;
  const int tid = threadIdx.x;

  if (tid < 128){
    float mc[3], lc[3];
    float M = -1e30f;
    for (int c = 0; c < NC; c++){
      mc[c] = mlg[(slotbase + c) * 256 + tid];
      lc[c] = mlg[(slotbase + c) * 256 + 128 + tid];
      M = fmaxf(M, mc[c]);
    }
    float L = 0.f;
    for (int c = 0; c < NC; c++){
      float wc = __expf(mc[c] - M);
      mc[c] = wc;
      L += lc[c] * wc;
    }
    float inv = 1.f / L;
    #pragma unroll
    for (int c = 0; c < 3; c++) wl[tid][c] = (c < NC) ? mc[c] * inv : 0.f;
  }
  __syncthreads();

  for (int it = 0; it < 32; it++){
    int idx = it * 256 + tid;                 // 128 rows x 64 chunks
    int row = idx >> 6, cv = idx & 63;
    float acc[8] = {0.f,0.f,0.f,0.f,0.f,0.f,0.f,0.f};
    for (int c = 0; c < NC; c++){
      float wc = wl[row][c];
      short8 v = *(const short8*)&Opart[(slotbase + c) * (QB * HH) + row * HH + cv * 8];
      #pragma unroll
      for (int j = 0; j < 8; j++){
        float f = __uint_as_float((unsigned)(unsigned short)v[j] << 16);
        acc[j] += f * wc;
      }
    }
    union { unsigned short u[8]; uint4 q; } rr;
    #pragma unroll
    for (int j = 0; j < 8; j++) rr.u[j] = f2bf(acc[j]);
    long dstoff = ((long)b * SS + qi * QB + row) * EE + n * HH + cv * 8;
    *(uint4*)&O[dstoff] = rr.q;
  }
}

// ---------------- host launch ----------------
extern "C" void kernel_launch(void* const* d_in, const int* in_sizes, int n_in,
                              void* d_out, int out_size, void* d_ws, size_t ws_size,
                              hipStream_t stream)
{
  const float* x   = (const float*)d_in[0];
  const float* Wq  = (const float*)d_in[1];
  const float* bq  = (const float*)d_in[2];
  const float* Wk  = (const float*)d_in[3];
  const float* bk  = (const float*)d_in[4];
  const float* Wv  = (const float*)d_in[5];
  const float* bv  = (const float*)d_in[6];
  const float* Wf  = (const float*)d_in[7];
  const float* bf_ = (const float*)d_in[8];
  const int* masked = (const int*)d_in[9];

  char* p = (char*)d_ws;
  const long TEN = (long)BB * SS * EE * 2;                 // 16 MiB per bf16 tensor
  unsigned short* xb  = (unsigned short*)p; p += TEN;
  unsigned short* Qb  = (unsigned short*)p; p += TEN;
  unsigned short* Kb  = (unsigned short*)p; p += TEN;
  unsigned short* Vt  = (unsigned short*)p; p += TEN;      // V^T, written directly by k_qkvall
  unsigned short* Ob  = (unsigned short*)p; p += TEN;      // combined O
  unsigned short* wqb = (unsigned short*)p; p += 2L * HH * HH * 2;
  unsigned short* wkb = (unsigned short*)p; p += 2L * HH * HH * 2;
  unsigned short* wvb = (unsigned short*)p; p += 2L * HH * HH * 2;
  unsigned short* wfb = (unsigned short*)p; p += (long)EE * EE * 2;
  unsigned short* Opart = (unsigned short*)p; p += 384L * QB * HH * 2;   // 48 MB
  float* mlg = (float*)p; p += 384L * 256 * 4;                           // 0.4 MB

  k_cvt_all<<<dim3(2048), 256, 0, stream>>>(x, Wq, Wk, Wv, Wf, xb, wqb, wkb, wvb, wfb);
  k_qkvall <<<dim3(SS / 128, HH / 128, 24), 256, 0, stream>>>(xb, wqb, wkb, wvb,
                                                              bq, bk, bv, Qb, Kb, Vt);
  k_flash14<<<dim3(256), 512, 0, stream>>>(Qb, Kb, Vt, Opart, mlg, Ob, masked);
  k_combine<<<dim3(128), 256, 0, stream>>>(Opart, mlg, Ob, masked);
  k_outproj<<<dim3((BB * SS) / 128, EE / 128, 1), 256, 0, stream>>>(Ob, wfb, bf_, (float*)d_out);
}